// Round 13
// baseline (18.028 us; speedup 1.0000x reference)
//
#include <hip/hip_runtime.h>
#include <math.h>

#define TLEN 1024

typedef int i32x2 __attribute__((ext_vector_type(2)));

__device__ __forceinline__ float2 cadd(float2 a, float2 b){ return make_float2(a.x+b.x, a.y+b.y); }
__device__ __forceinline__ float2 csub(float2 a, float2 b){ return make_float2(a.x-b.x, a.y-b.y); }
__device__ __forceinline__ float2 cmul(float2 a, float2 b){
    return make_float2(fmaf(a.x, b.x, -(a.y*b.y)), fmaf(a.x, b.y, a.y*b.x));
}
__device__ __forceinline__ float2 cmulnegi(float2 a){ return make_float2(a.y, -a.x); }  // a * (-i)
__device__ __forceinline__ float2 cmulposi(float2 a){ return make_float2(-a.y, a.x); }  // a * (+i)
__device__ __forceinline__ int bitrev6(int l){
    return ((l & 1) << 5) | ((l & 2) << 3) | ((l & 4) << 1)
         | ((l & 8) >> 1) | ((l & 16) >> 3) | ((l & 32) >> 5);
}

// ---- cross-lane partner primitives (verified R4/R12) ----
#define DPP_XOR1  0xB1   // quad_perm [1,0,3,2]
#define DPP_XOR2  0x4E   // quad_perm [2,3,0,1]
#define DPP_XOR8  0x128  // row_ror:8
#define SWZ_XOR4  0x101F // bitmode xor=4

template<int CTRL>
__device__ __forceinline__ float2 dpp2(float2 v){
    return make_float2(
        __int_as_float(__builtin_amdgcn_mov_dpp(__float_as_int(v.x), CTRL, 0xF, 0xF, false)),
        __int_as_float(__builtin_amdgcn_mov_dpp(__float_as_int(v.y), CTRL, 0xF, 0xF, false)));
}
template<int PAT>
__device__ __forceinline__ float2 swz2(float2 v){
    return make_float2(
        __int_as_float(__builtin_amdgcn_ds_swizzle(__float_as_int(v.x), PAT)),
        __int_as_float(__builtin_amdgcn_ds_swizzle(__float_as_int(v.y), PAT)));
}
// xor32 exchange via v_permlane32_swap (VALU): result = up ? r[0] : r[1]
__device__ __forceinline__ float p32f(float v, bool up){
#if __has_builtin(__builtin_amdgcn_permlane32_swap)
    i32x2 r = __builtin_amdgcn_permlane32_swap(__float_as_int(v), __float_as_int(v), false, false);
    return __int_as_float(up ? r[0] : r[1]);
#else
    int a = __float_as_int(v), b = __float_as_int(v);
    asm("v_permlane32_swap_b32 %0, %1" : "+v"(a), "+v"(b));
    return __int_as_float(up ? a : b);
#endif
}
__device__ __forceinline__ float2 p32_2(float2 v, bool up){
    return make_float2(p32f(v.x, up), p32f(v.y, up));
}
// xor16 exchange via v_permlane16_swap (VALU, gfx950): same select pattern,
// up = (lane & 16). Replaces ds_swizzle xor16 (removes DS latency hop).
__device__ __forceinline__ float p16f(float v, bool up){
#if __has_builtin(__builtin_amdgcn_permlane16_swap)
    i32x2 r = __builtin_amdgcn_permlane16_swap(__float_as_int(v), __float_as_int(v), false, false);
    return __int_as_float(up ? r[0] : r[1]);
#else
    int a = __float_as_int(v), b = __float_as_int(v);
    asm("v_permlane16_swap_b32 %0, %1" : "+v"(a), "+v"(b));
    return __int_as_float(up ? a : b);
#endif
}
__device__ __forceinline__ float2 p16_2(float2 v, bool up){
    return make_float2(p16f(v.x, up), p16f(v.y, up));
}

// selected output k of DFT-4 (k wave-uniform)
__device__ __forceinline__ float2 combine4(float2 x0, float2 x1, float2 x2, float2 x3, int k){
    float2 e = cadd(x0, x2), f = csub(x0, x2);
    float2 g = cadd(x1, x3), h = csub(x1, x3);
    if (k == 0) return cadd(e, g);
    if (k == 1) return cadd(f, cmulnegi(h));
    if (k == 2) return csub(e, g);
    return cadd(f, cmulposi(h));
}
// selected output k of DFT-8 (k wave-uniform): y_k = E_{k&3} +/- W8^{k&3} O_{k&3}
__device__ __forceinline__ float2 combine8(const float2 x[8], int k){
    const float H = 0.70710678118654752440f;
    float2 E = combine4(x[0], x[2], x[4], x[6], k & 3);
    float2 O = combine4(x[1], x[3], x[5], x[7], k & 3);
    float2 WO;
    switch (k & 3){
        case 0:  WO = O; break;
        case 1:  WO = cmul(O, make_float2( H, -H)); break;
        case 2:  WO = cmulnegi(O); break;
        default: WO = cmul(O, make_float2(-H, -H)); break;
    }
    return (k < 4) ? cadd(E, WO) : csub(E, WO);
}

// ---- cross-lane FFT-64 over lanes, 2 regs (verified R12) ----
template<bool TW, typename F>
__device__ __forceinline__ void dif_stage2(float2 z[2], F partner, float sg, float2 w){
    #pragma unroll
    for (int r = 0; r < 2; ++r){
        float2 o = partner(z[r]);
        float2 pre = make_float2(fmaf(sg, z[r].x, o.x), fmaf(sg, z[r].y, o.y));
        z[r] = TW ? cmul(pre, w) : pre;
    }
}
template<bool TW, typename F>
__device__ __forceinline__ void dit_stage2(float2 z[2], F partner, float sg, float2 w){
    #pragma unroll
    for (int r = 0; r < 2; ++r){
        float2 zz = TW ? cmul(z[r], w) : z[r];
        float2 o = partner(zz);
        z[r] = make_float2(fmaf(sg, zz.x, o.x), fmaf(sg, zz.y, o.y));
    }
}
__device__ __forceinline__ void xfft_dif2(float2 z[2], const float2 Wt[5], int lane){
    const float2 ONE = make_float2(1.0f, 0.0f);
    {   const bool up = (lane & 32) != 0; const float sg = up ? -1.0f : 1.0f;
        dif_stage2<true>(z, [&](float2 v){ return p32_2(v, up); }, sg, up ? Wt[4] : ONE); }
    {   const bool up = (lane & 16) != 0; const float sg = up ? -1.0f : 1.0f;
        dif_stage2<true>(z, [&](float2 v){ return p16_2(v, up); }, sg, up ? Wt[3] : ONE); }
    {   const bool up = (lane & 8) != 0;  const float sg = up ? -1.0f : 1.0f;
        dif_stage2<true>(z, [](float2 v){ return dpp2<DPP_XOR8>(v); }, sg, up ? Wt[2] : ONE); }
    {   const bool up = (lane & 4) != 0;  const float sg = up ? -1.0f : 1.0f;
        dif_stage2<true>(z, [](float2 v){ return swz2<SWZ_XOR4>(v); }, sg, up ? Wt[1] : ONE); }
    {   const bool up = (lane & 2) != 0;  const float sg = up ? -1.0f : 1.0f;
        dif_stage2<true>(z, [](float2 v){ return dpp2<DPP_XOR2>(v); }, sg, up ? Wt[0] : ONE); }
    {   const float sg = (lane & 1) ? -1.0f : 1.0f;
        dif_stage2<false>(z, [](float2 v){ return dpp2<DPP_XOR1>(v); }, sg, ONE); }
}
__device__ __forceinline__ void xfft_dit2(float2 z[2], const float2 Wt[5], int lane){
    const float2 ONE = make_float2(1.0f, 0.0f);
    {   const float sg = (lane & 1) ? -1.0f : 1.0f;
        dit_stage2<false>(z, [](float2 v){ return dpp2<DPP_XOR1>(v); }, sg, ONE); }
    {   const bool up = (lane & 2) != 0;  const float sg = up ? -1.0f : 1.0f;
        dit_stage2<true>(z, [](float2 v){ return dpp2<DPP_XOR2>(v); }, sg, up ? Wt[0] : ONE); }
    {   const bool up = (lane & 4) != 0;  const float sg = up ? -1.0f : 1.0f;
        dit_stage2<true>(z, [](float2 v){ return swz2<SWZ_XOR4>(v); }, sg, up ? Wt[1] : ONE); }
    {   const bool up = (lane & 8) != 0;  const float sg = up ? -1.0f : 1.0f;
        dit_stage2<true>(z, [](float2 v){ return dpp2<DPP_XOR8>(v); }, sg, up ? Wt[2] : ONE); }
    {   const bool up = (lane & 16) != 0; const float sg = up ? -1.0f : 1.0f;
        dit_stage2<true>(z, [&](float2 v){ return p16_2(v, up); }, sg, up ? Wt[3] : ONE); }
    {   const bool up = (lane & 32) != 0; const float sg = up ? -1.0f : 1.0f;
        dit_stage2<true>(z, [&](float2 v){ return p32_2(v, up); }, sg, up ? Wt[4] : ONE); }
}

// ============================================================================
// fused v5: R12's 8-wave chain with xor16 moved off the DS pipe
// (v_permlane16_swap). 6 barriers; every wave chains AND dots its own row.
// ============================================================================
__global__ __launch_bounds__(512, 4)
void fused_kernel(const float* __restrict__ X,
                  const float* __restrict__ W,
                  float* __restrict__ out)
{
    __shared__ float2 xb0[16 * 64];    // exchange buffer A (8 KiB)
    __shared__ float2 xb1[16 * 64];    // exchange buffer B / final a (8 KiB)

    const int lane = threadIdx.x & 63;
    const int wid  = threadIdx.x >> 6;   // 0..7
    const int row  = blockIdx.x * 8 + wid;

    // ---- prefetch own row of X (no wait until dot phase) ----
    float4 xr[4];
    {
        const float4* px = (const float4*)(X + (size_t)row * TLEN + lane * 16);
        #pragma unroll
        for (int i = 0; i < 4; ++i) xr[i] = px[i];
    }

    // ================= prep chain (all 8 waves) =================
    const int c = bitrev6(lane);
    float2 Wt[5];
    #pragma unroll
    for (int k = 0; k < 5; ++k){
        const int h = 2 << k;
        float sv, cv;
        __sincosf(-3.14159265358979323846f * (float)(lane & (h - 1)) / (float)h, &sv, &cv);
        Wt[k] = make_float2(cv, sv);
    }
    // W16^{wid} (wave-uniform)
    float2 w16;
    {
        float sv, cv;
        __sincosf(-3.14159265358979323846f * (float)wid / 8.0f, &sv, &cv);
        w16 = make_float2(cv, sv);
    }
    // mid twiddles wmv[j] = W1024^{c*(2*wid+j)}
    float2 wmv[2];
    {
        const float theta = -6.28318530717958647692f * (float)c / 1024.0f;
        float sv, cv;
        __sincosf(theta * (float)(2 * wid), &sv, &cv); wmv[0] = make_float2(cv, sv);
        __sincosf(theta, &sv, &cv);                    wmv[1] = cmul(wmv[0], make_float2(cv, sv));
    }

    float2 z[2];
    z[0] = make_float2(1.0f, 0.0f);   // F e0 (uniform)
    z[1] = make_float2(1.0f, 0.0f);

    auto Mstr = [&](){   // strided: partner flips c bit0 = lane bit5
        const bool upm = (lane & 32) != 0;
        const float sgm = upm ? -1.0f : 1.0f;
        #pragma unroll
        for (int j = 0; j < 2; ++j){
            float2 o = p32_2(z[j], upm);
            z[j] = make_float2(fmaf(sgm, z[j].x, o.x), fmaf(sgm, z[j].y, o.y));
        }
    };
    auto Mcon = [&](){   // consecutive: pair is (j=0, j=1)
        float2 a0 = z[0], b0 = z[1];
        z[0] = cadd(a0, b0); z[1] = csub(a0, b0);
    };
    auto Dstr = [&](int l){  // t = 64*(wid + 8j) + c
        const float* p = W + l * TLEN + c + 64 * wid;
        #pragma unroll
        for (int j = 0; j < 2; ++j){
            float sv, cv; __sincosf(p[j << 9], &sv, &cv);
            z[j] = cmul(z[j], make_float2(cv, sv));
        }
    };
    auto Dcon = [&](int l){  // t = 16*lane + 2*wid + j
        float2 wv = *(const float2*)(W + l * TLEN + 16 * lane + 2 * wid);
        float ws[2] = {wv.x, wv.y};
        #pragma unroll
        for (int j = 0; j < 2; ++j){
            float sv, cv; __sincosf(ws[j], &sv, &cv);
            z[j] = cmul(z[j], make_float2(cv, sv));
        }
    };
    auto midtw = [&](){
        z[0] = cmul(z[0], wmv[0]);
        z[1] = cmul(z[1], wmv[1]);
    };
    // FFT-16 over r, input (w,j) holds r = 2w+j -> output (w,j) holds X16[w+8j]
    auto fft16A = [&](){
        #pragma unroll
        for (int j = 0; j < 2; ++j) xb1[(wid * 2 + j) * 64 + lane] = z[j];
        __syncthreads();
        float2 u[2];
        #pragma unroll
        for (int j = 0; j < 2; ++j){
            float2 x[8];
            #pragma unroll
            for (int w = 0; w < 8; ++w) x[w] = xb1[(2 * w + j) * 64 + lane];
            u[j] = combine8(x, wid);      // k1 = wid
        }
        u[1] = cmul(u[1], w16);           // W16^{j*k1}
        z[0] = cadd(u[0], u[1]);          // FFT-2 over j -> k2
        z[1] = csub(u[0], u[1]);
    };
    // FFT-16 over r, input (w,j) holds r = w+8j -> output (w,j) holds X16[2w+j]
    auto fft16B = [&](){
        float2 u[2];
        u[0] = cadd(z[0], z[1]);          // FFT-2 over j -> k_lo
        u[1] = csub(z[0], z[1]);
        u[1] = cmul(u[1], w16);           // W16^{w*k_lo}
        #pragma unroll
        for (int j = 0; j < 2; ++j) xb0[(wid * 2 + j) * 64 + lane] = u[j];
        __syncthreads();
        #pragma unroll
        for (int j = 0; j < 2; ++j){
            float2 x[8];
            #pragma unroll
            for (int w = 0; w < 8; ++w) x[w] = xb0[(2 * w + j) * 64 + lane];
            z[j] = combine8(x, wid);      // k1 = wid -> X16[j + 2*wid]
        }
    };
    auto dftA = [&](){ xfft_dif2(z, Wt, lane); midtw(); fft16A(); };
    auto dftB = [&](){ fft16B(); midtw(); xfft_dit2(z, Wt, lane); };

    // chain: v = e0; for l=5..0: v = D_l M F v.  (F#1 folded into init)
    Mstr(); Dstr(5);
    #pragma unroll 1
    for (int lp = 0; lp < 2; ++lp){
        dftB(); Mcon(); Dcon(4 - 2 * lp);   // barrier 1,3
        dftA(); Mstr(); Dstr(3 - 2 * lp);   // barrier 2,4
    }
    dftB(); Mcon(); Dcon(0);                // barrier 5
    // store a (consecutive layout): a[16*lane + 2*wid + j] -> xb1[(2*wid+j)*64 + lane]
    #pragma unroll
    for (int j = 0; j < 2; ++j) xb1[(2 * wid + j) * 64 + lane] = z[j];
    __syncthreads();                        // barrier 6

    // ================= dot phase: every wave its own row =================
    float re = 0.0f, im = 0.0f;
    #pragma unroll
    for (int i = 0; i < 4; ++i){
        float4 xv = xr[i];
        float xs[4] = {xv.x, xv.y, xv.z, xv.w};
        #pragma unroll
        for (int j = 0; j < 4; ++j){
            float2 av = xb1[(4 * i + j) * 64 + lane];   // a[16*lane + 4i + j]
            float x  = fminf(fmaxf(xs[j], -0.999f), 0.999f);
            float cc = sqrtf(fmaf(-x, x, 1.0f));
            re = fmaf(av.x, cc, re);  re = fmaf(-av.y, x,  re);
            im = fmaf(av.x, x,  im);  im = fmaf( av.y, cc, im);
        }
    }

    float2 s = make_float2(re, im);
    s = cadd(s, dpp2<DPP_XOR1>(s));
    s = cadd(s, dpp2<DPP_XOR2>(s));
    s = cadd(s, swz2<SWZ_XOR4>(s));
    s = cadd(s, dpp2<DPP_XOR8>(s));
    s = cadd(s, p16_2(s, (lane & 16) != 0));
    s = cadd(s, p32_2(s, (lane & 32) != 0));

    if (lane == 0){
        out[row] = fmaf(s.y * rsqrtf(fmaf(s.x, s.x, s.y * s.y)), 0.5f, 0.5f);
    }
}

extern "C" void kernel_launch(void* const* d_in, const int* in_sizes, int n_in,
                              void* d_out, int out_size, void* d_ws, size_t ws_size,
                              hipStream_t stream) {
    const float* X = (const float*)d_in[0];   // [4096, 1024]
    const float* W = (const float*)d_in[1];   // [6*1024]
    float* out = (float*)d_out;               // [4096]
    (void)in_sizes; (void)n_in; (void)out_size; (void)d_ws; (void)ws_size;

    fused_kernel<<<4096 / 8, 512, 0, stream>>>(X, W, out);
}

// Round 14
// 15.339 us; speedup vs baseline: 1.1753x; 1.1753x over previous
//
#include <hip/hip_runtime.h>
#include <math.h>

#define TLEN 1024

typedef int i32x2 __attribute__((ext_vector_type(2)));

__device__ __forceinline__ float2 cadd(float2 a, float2 b){ return make_float2(a.x+b.x, a.y+b.y); }
__device__ __forceinline__ float2 csub(float2 a, float2 b){ return make_float2(a.x-b.x, a.y-b.y); }
__device__ __forceinline__ float2 cmul(float2 a, float2 b){
    return make_float2(fmaf(a.x, b.x, -(a.y*b.y)), fmaf(a.x, b.y, a.y*b.x));
}
__device__ __forceinline__ float2 cmulnegi(float2 a){ return make_float2(a.y, -a.x); }  // a * (-i)
__device__ __forceinline__ float2 cmulposi(float2 a){ return make_float2(-a.y, a.x); }  // a * (+i)
__device__ __forceinline__ int bitrev6(int l){
    return ((l & 1) << 5) | ((l & 2) << 3) | ((l & 4) << 1)
         | ((l & 8) >> 1) | ((l & 16) >> 3) | ((l & 32) >> 5);
}

// ---- cross-lane partner primitives (verified R4/R12) ----
#define DPP_XOR1  0xB1   // quad_perm [1,0,3,2]
#define DPP_XOR2  0x4E   // quad_perm [2,3,0,1]
#define DPP_XOR8  0x128  // row_ror:8
#define SWZ_XOR4  0x101F // bitmode xor=4
#define SWZ_XOR16 0x401F // bitmode xor=16

template<int CTRL>
__device__ __forceinline__ float2 dpp2(float2 v){
    return make_float2(
        __int_as_float(__builtin_amdgcn_mov_dpp(__float_as_int(v.x), CTRL, 0xF, 0xF, false)),
        __int_as_float(__builtin_amdgcn_mov_dpp(__float_as_int(v.y), CTRL, 0xF, 0xF, false)));
}
template<int PAT>
__device__ __forceinline__ float2 swz2(float2 v){
    return make_float2(
        __int_as_float(__builtin_amdgcn_ds_swizzle(__float_as_int(v.x), PAT)),
        __int_as_float(__builtin_amdgcn_ds_swizzle(__float_as_int(v.y), PAT)));
}
__device__ __forceinline__ float p32f(float v, bool up){
#if __has_builtin(__builtin_amdgcn_permlane32_swap)
    i32x2 r = __builtin_amdgcn_permlane32_swap(__float_as_int(v), __float_as_int(v), false, false);
    return __int_as_float(up ? r[0] : r[1]);
#else
    int a = __float_as_int(v), b = __float_as_int(v);
    asm("v_permlane32_swap_b32 %0, %1" : "+v"(a), "+v"(b));
    return __int_as_float(up ? a : b);
#endif
}
__device__ __forceinline__ float2 p32_2(float2 v, bool up){
    return make_float2(p32f(v.x, up), p32f(v.y, up));
}

// selected output k of DFT-4 (k wave-uniform)
__device__ __forceinline__ float2 combine4(float2 x0, float2 x1, float2 x2, float2 x3, int k){
    float2 e = cadd(x0, x2), f = csub(x0, x2);
    float2 g = cadd(x1, x3), h = csub(x1, x3);
    if (k == 0) return cadd(e, g);
    if (k == 1) return cadd(f, cmulnegi(h));
    if (k == 2) return csub(e, g);
    return cadd(f, cmulposi(h));
}
// selected output k of DFT-8 (k wave-uniform)
__device__ __forceinline__ float2 combine8(const float2 x[8], int k){
    const float H = 0.70710678118654752440f;
    float2 E = combine4(x[0], x[2], x[4], x[6], k & 3);
    float2 O = combine4(x[1], x[3], x[5], x[7], k & 3);
    float2 WO;
    switch (k & 3){
        case 0:  WO = O; break;
        case 1:  WO = cmul(O, make_float2( H, -H)); break;
        case 2:  WO = cmulnegi(O); break;
        default: WO = cmul(O, make_float2(-H, -H)); break;
    }
    return (k < 4) ? cadd(E, WO) : csub(E, WO);
}

// ---- cross-lane FFT-64 over lanes, 2 regs (verified R12) ----
template<bool TW, typename F>
__device__ __forceinline__ void dif_stage2(float2 z[2], F partner, float sg, float2 w){
    #pragma unroll
    for (int r = 0; r < 2; ++r){
        float2 o = partner(z[r]);
        float2 pre = make_float2(fmaf(sg, z[r].x, o.x), fmaf(sg, z[r].y, o.y));
        z[r] = TW ? cmul(pre, w) : pre;
    }
}
template<bool TW, typename F>
__device__ __forceinline__ void dit_stage2(float2 z[2], F partner, float sg, float2 w){
    #pragma unroll
    for (int r = 0; r < 2; ++r){
        float2 zz = TW ? cmul(z[r], w) : z[r];
        float2 o = partner(zz);
        z[r] = make_float2(fmaf(sg, zz.x, o.x), fmaf(sg, zz.y, o.y));
    }
}
__device__ __forceinline__ void xfft_dif2(float2 z[2], const float2 Wt[5], int lane){
    const float2 ONE = make_float2(1.0f, 0.0f);
    {   const bool up = (lane & 32) != 0; const float sg = up ? -1.0f : 1.0f;
        dif_stage2<true>(z, [&](float2 v){ return p32_2(v, up); }, sg, up ? Wt[4] : ONE); }
    {   const bool up = (lane & 16) != 0; const float sg = up ? -1.0f : 1.0f;
        dif_stage2<true>(z, [](float2 v){ return swz2<SWZ_XOR16>(v); }, sg, up ? Wt[3] : ONE); }
    {   const bool up = (lane & 8) != 0;  const float sg = up ? -1.0f : 1.0f;
        dif_stage2<true>(z, [](float2 v){ return dpp2<DPP_XOR8>(v); }, sg, up ? Wt[2] : ONE); }
    {   const bool up = (lane & 4) != 0;  const float sg = up ? -1.0f : 1.0f;
        dif_stage2<true>(z, [](float2 v){ return swz2<SWZ_XOR4>(v); }, sg, up ? Wt[1] : ONE); }
    {   const bool up = (lane & 2) != 0;  const float sg = up ? -1.0f : 1.0f;
        dif_stage2<true>(z, [](float2 v){ return dpp2<DPP_XOR2>(v); }, sg, up ? Wt[0] : ONE); }
    {   const float sg = (lane & 1) ? -1.0f : 1.0f;
        dif_stage2<false>(z, [](float2 v){ return dpp2<DPP_XOR1>(v); }, sg, ONE); }
}
__device__ __forceinline__ void xfft_dit2(float2 z[2], const float2 Wt[5], int lane){
    const float2 ONE = make_float2(1.0f, 0.0f);
    {   const float sg = (lane & 1) ? -1.0f : 1.0f;
        dit_stage2<false>(z, [](float2 v){ return dpp2<DPP_XOR1>(v); }, sg, ONE); }
    {   const bool up = (lane & 2) != 0;  const float sg = up ? -1.0f : 1.0f;
        dit_stage2<true>(z, [](float2 v){ return dpp2<DPP_XOR2>(v); }, sg, up ? Wt[0] : ONE); }
    {   const bool up = (lane & 4) != 0;  const float sg = up ? -1.0f : 1.0f;
        dit_stage2<true>(z, [](float2 v){ return swz2<SWZ_XOR4>(v); }, sg, up ? Wt[1] : ONE); }
    {   const bool up = (lane & 8) != 0;  const float sg = up ? -1.0f : 1.0f;
        dit_stage2<true>(z, [](float2 v){ return dpp2<DPP_XOR8>(v); }, sg, up ? Wt[2] : ONE); }
    {   const bool up = (lane & 16) != 0; const float sg = up ? -1.0f : 1.0f;
        dit_stage2<true>(z, [](float2 v){ return swz2<SWZ_XOR16>(v); }, sg, up ? Wt[3] : ONE); }
    {   const bool up = (lane & 32) != 0; const float sg = up ? -1.0f : 1.0f;
        dit_stage2<true>(z, [&](float2 v){ return p32_2(v, up); }, sg, up ? Wt[4] : ONE); }
}

// ============================================================================
// fused v6: 16 rows/block (1024 threads, grid 256 = 1 block/CU) — halves the
// chip-wide redundant chain work. Chain = R12's 8-wave version on waves 0-7;
// waves 8-15 spin the 6 matching barriers; all 16 waves dot their own row.
// ============================================================================
__global__ __launch_bounds__(1024, 1)
void fused_kernel(const float* __restrict__ X,
                  const float* __restrict__ W,
                  float* __restrict__ out)
{
    __shared__ float2 xb0[16 * 64];    // exchange buffer A (8 KiB)
    __shared__ float2 xb1[16 * 64];    // exchange buffer B / final a (8 KiB)

    const int lane = threadIdx.x & 63;
    const int wid  = threadIdx.x >> 6;   // 0..15
    const int row  = blockIdx.x * 16 + wid;

    // ---- prefetch own row of X (no wait until dot phase) ----
    float4 xr[4];
    {
        const float4* px = (const float4*)(X + (size_t)row * TLEN + lane * 16);
        #pragma unroll
        for (int i = 0; i < 4; ++i) xr[i] = px[i];
    }

    if (wid < 8){
        // ================= prep chain (waves 0-7), verbatim R12 =================
        const int c = bitrev6(lane);
        float2 Wt[5];
        #pragma unroll
        for (int k = 0; k < 5; ++k){
            const int h = 2 << k;
            float sv, cv;
            __sincosf(-3.14159265358979323846f * (float)(lane & (h - 1)) / (float)h, &sv, &cv);
            Wt[k] = make_float2(cv, sv);
        }
        float2 w16;
        {
            float sv, cv;
            __sincosf(-3.14159265358979323846f * (float)wid / 8.0f, &sv, &cv);
            w16 = make_float2(cv, sv);
        }
        float2 wmv[2];
        {
            const float theta = -6.28318530717958647692f * (float)c / 1024.0f;
            float sv, cv;
            __sincosf(theta * (float)(2 * wid), &sv, &cv); wmv[0] = make_float2(cv, sv);
            __sincosf(theta, &sv, &cv);                    wmv[1] = cmul(wmv[0], make_float2(cv, sv));
        }

        float2 z[2];
        z[0] = make_float2(1.0f, 0.0f);   // F e0 (uniform)
        z[1] = make_float2(1.0f, 0.0f);

        auto Mstr = [&](){
            const bool upm = (lane & 32) != 0;
            const float sgm = upm ? -1.0f : 1.0f;
            #pragma unroll
            for (int j = 0; j < 2; ++j){
                float2 o = p32_2(z[j], upm);
                z[j] = make_float2(fmaf(sgm, z[j].x, o.x), fmaf(sgm, z[j].y, o.y));
            }
        };
        auto Mcon = [&](){
            float2 a0 = z[0], b0 = z[1];
            z[0] = cadd(a0, b0); z[1] = csub(a0, b0);
        };
        auto Dstr = [&](int l){  // t = 64*(wid + 8j) + c
            const float* p = W + l * TLEN + c + 64 * wid;
            #pragma unroll
            for (int j = 0; j < 2; ++j){
                float sv, cv; __sincosf(p[j << 9], &sv, &cv);
                z[j] = cmul(z[j], make_float2(cv, sv));
            }
        };
        auto Dcon = [&](int l){  // t = 16*lane + 2*wid + j
            float2 wv = *(const float2*)(W + l * TLEN + 16 * lane + 2 * wid);
            float ws[2] = {wv.x, wv.y};
            #pragma unroll
            for (int j = 0; j < 2; ++j){
                float sv, cv; __sincosf(ws[j], &sv, &cv);
                z[j] = cmul(z[j], make_float2(cv, sv));
            }
        };
        auto midtw = [&](){
            z[0] = cmul(z[0], wmv[0]);
            z[1] = cmul(z[1], wmv[1]);
        };
        auto fft16A = [&](){
            #pragma unroll
            for (int j = 0; j < 2; ++j) xb1[(wid * 2 + j) * 64 + lane] = z[j];
            __syncthreads();
            float2 u[2];
            #pragma unroll
            for (int j = 0; j < 2; ++j){
                float2 x[8];
                #pragma unroll
                for (int w = 0; w < 8; ++w) x[w] = xb1[(2 * w + j) * 64 + lane];
                u[j] = combine8(x, wid);
            }
            u[1] = cmul(u[1], w16);
            z[0] = cadd(u[0], u[1]);
            z[1] = csub(u[0], u[1]);
        };
        auto fft16B = [&](){
            float2 u[2];
            u[0] = cadd(z[0], z[1]);
            u[1] = csub(z[0], z[1]);
            u[1] = cmul(u[1], w16);
            #pragma unroll
            for (int j = 0; j < 2; ++j) xb0[(wid * 2 + j) * 64 + lane] = u[j];
            __syncthreads();
            #pragma unroll
            for (int j = 0; j < 2; ++j){
                float2 x[8];
                #pragma unroll
                for (int w = 0; w < 8; ++w) x[w] = xb0[(2 * w + j) * 64 + lane];
                z[j] = combine8(x, wid);
            }
        };
        auto dftA = [&](){ xfft_dif2(z, Wt, lane); midtw(); fft16A(); };
        auto dftB = [&](){ fft16B(); midtw(); xfft_dit2(z, Wt, lane); };

        // chain: v = e0; for l=5..0: v = D_l M F v.  (F#1 folded into init)
        Mstr(); Dstr(5);
        #pragma unroll 1
        for (int lp = 0; lp < 2; ++lp){
            dftB(); Mcon(); Dcon(4 - 2 * lp);   // barrier 1,3
            dftA(); Mstr(); Dstr(3 - 2 * lp);   // barrier 2,4
        }
        dftB(); Mcon(); Dcon(0);                // barrier 5
        // store a (consecutive): a[16*lane + 2*wid + j] -> xb1[(2*wid+j)*64 + lane]
        #pragma unroll
        for (int j = 0; j < 2; ++j) xb1[(2 * wid + j) * 64 + lane] = z[j];
        __syncthreads();                        // barrier 6
    } else {
        // waves 8-15: match the chain's 6 barriers
        #pragma unroll 1
        for (int b = 0; b < 6; ++b) __syncthreads();
    }

    // ================= dot phase: every wave its own row =================
    float re = 0.0f, im = 0.0f;
    #pragma unroll
    for (int i = 0; i < 4; ++i){
        float4 xv = xr[i];
        float xs[4] = {xv.x, xv.y, xv.z, xv.w};
        #pragma unroll
        for (int j = 0; j < 4; ++j){
            float2 av = xb1[(4 * i + j) * 64 + lane];   // a[16*lane + 4i + j]
            float x  = fminf(fmaxf(xs[j], -0.999f), 0.999f);
            float cc = sqrtf(fmaf(-x, x, 1.0f));
            re = fmaf(av.x, cc, re);  re = fmaf(-av.y, x,  re);
            im = fmaf(av.x, x,  im);  im = fmaf( av.y, cc, im);
        }
    }

    float2 s = make_float2(re, im);
    s = cadd(s, dpp2<DPP_XOR1>(s));
    s = cadd(s, dpp2<DPP_XOR2>(s));
    s = cadd(s, swz2<SWZ_XOR4>(s));
    s = cadd(s, dpp2<DPP_XOR8>(s));
    s = cadd(s, swz2<SWZ_XOR16>(s));
    s = cadd(s, p32_2(s, (lane & 32) != 0));

    if (lane == 0){
        out[row] = fmaf(s.y * rsqrtf(fmaf(s.x, s.x, s.y * s.y)), 0.5f, 0.5f);
    }
}

extern "C" void kernel_launch(void* const* d_in, const int* in_sizes, int n_in,
                              void* d_out, int out_size, void* d_ws, size_t ws_size,
                              hipStream_t stream) {
    const float* X = (const float*)d_in[0];   // [4096, 1024]
    const float* W = (const float*)d_in[1];   // [6*1024]
    float* out = (float*)d_out;               // [4096]
    (void)in_sizes; (void)n_in; (void)out_size; (void)d_ws; (void)ws_size;

    fused_kernel<<<4096 / 16, 1024, 0, stream>>>(X, W, out);
}

// Round 15
// 15.266 us; speedup vs baseline: 1.1809x; 1.0048x over previous
//
#include <hip/hip_runtime.h>
#include <math.h>

#define TLEN 1024

typedef int i32x2 __attribute__((ext_vector_type(2)));

__device__ __forceinline__ float2 cadd(float2 a, float2 b){ return make_float2(a.x+b.x, a.y+b.y); }
__device__ __forceinline__ float2 csub(float2 a, float2 b){ return make_float2(a.x-b.x, a.y-b.y); }
__device__ __forceinline__ float2 cmul(float2 a, float2 b){
    return make_float2(fmaf(a.x, b.x, -(a.y*b.y)), fmaf(a.x, b.y, a.y*b.x));
}
__device__ __forceinline__ float2 cmulnegi(float2 a){ return make_float2(a.y, -a.x); }  // a * (-i)
__device__ __forceinline__ float2 cmulposi(float2 a){ return make_float2(-a.y, a.x); }  // a * (+i)
__device__ __forceinline__ int bitrev6(int l){
    return ((l & 1) << 5) | ((l & 2) << 3) | ((l & 4) << 1)
         | ((l & 8) >> 1) | ((l & 16) >> 3) | ((l & 32) >> 5);
}

// ---- cross-lane partner primitives (verified R4/R12) ----
#define DPP_XOR1  0xB1   // quad_perm [1,0,3,2]
#define DPP_XOR2  0x4E   // quad_perm [2,3,0,1]
#define DPP_XOR8  0x128  // row_ror:8
#define SWZ_XOR4  0x101F // bitmode xor=4
#define SWZ_XOR16 0x401F // bitmode xor=16

template<int CTRL>
__device__ __forceinline__ float2 dpp2(float2 v){
    return make_float2(
        __int_as_float(__builtin_amdgcn_mov_dpp(__float_as_int(v.x), CTRL, 0xF, 0xF, false)),
        __int_as_float(__builtin_amdgcn_mov_dpp(__float_as_int(v.y), CTRL, 0xF, 0xF, false)));
}
template<int PAT>
__device__ __forceinline__ float2 swz2(float2 v){
    return make_float2(
        __int_as_float(__builtin_amdgcn_ds_swizzle(__float_as_int(v.x), PAT)),
        __int_as_float(__builtin_amdgcn_ds_swizzle(__float_as_int(v.y), PAT)));
}
__device__ __forceinline__ float p32f(float v, bool up){
#if __has_builtin(__builtin_amdgcn_permlane32_swap)
    i32x2 r = __builtin_amdgcn_permlane32_swap(__float_as_int(v), __float_as_int(v), false, false);
    return __int_as_float(up ? r[0] : r[1]);
#else
    int a = __float_as_int(v), b = __float_as_int(v);
    asm("v_permlane32_swap_b32 %0, %1" : "+v"(a), "+v"(b));
    return __int_as_float(up ? a : b);
#endif
}
__device__ __forceinline__ float2 p32_2(float2 v, bool up){
    return make_float2(p32f(v.x, up), p32f(v.y, up));
}

// selected output k of DFT-4 (k wave-uniform)
__device__ __forceinline__ float2 combine4(float2 x0, float2 x1, float2 x2, float2 x3, int k){
    float2 e = cadd(x0, x2), f = csub(x0, x2);
    float2 g = cadd(x1, x3), h = csub(x1, x3);
    if (k == 0) return cadd(e, g);
    if (k == 1) return cadd(f, cmulnegi(h));
    if (k == 2) return csub(e, g);
    return cadd(f, cmulposi(h));
}
// selected output k of DFT-8 (k wave-uniform)
__device__ __forceinline__ float2 combine8(const float2 x[8], int k){
    const float H = 0.70710678118654752440f;
    float2 E = combine4(x[0], x[2], x[4], x[6], k & 3);
    float2 O = combine4(x[1], x[3], x[5], x[7], k & 3);
    float2 WO;
    switch (k & 3){
        case 0:  WO = O; break;
        case 1:  WO = cmul(O, make_float2( H, -H)); break;
        case 2:  WO = cmulnegi(O); break;
        default: WO = cmul(O, make_float2(-H, -H)); break;
    }
    return (k < 4) ? cadd(E, WO) : csub(E, WO);
}

// ---- cross-lane FFT-64 over lanes, 2 regs (verified R12) ----
template<bool TW, typename F>
__device__ __forceinline__ void dif_stage2(float2 z[2], F partner, float sg, float2 w){
    #pragma unroll
    for (int r = 0; r < 2; ++r){
        float2 o = partner(z[r]);
        float2 pre = make_float2(fmaf(sg, z[r].x, o.x), fmaf(sg, z[r].y, o.y));
        z[r] = TW ? cmul(pre, w) : pre;
    }
}
template<bool TW, typename F>
__device__ __forceinline__ void dit_stage2(float2 z[2], F partner, float sg, float2 w){
    #pragma unroll
    for (int r = 0; r < 2; ++r){
        float2 zz = TW ? cmul(z[r], w) : z[r];
        float2 o = partner(zz);
        z[r] = make_float2(fmaf(sg, zz.x, o.x), fmaf(sg, zz.y, o.y));
    }
}
__device__ __forceinline__ void xfft_dif2(float2 z[2], const float2 Wt[5], int lane){
    const float2 ONE = make_float2(1.0f, 0.0f);
    {   const bool up = (lane & 32) != 0; const float sg = up ? -1.0f : 1.0f;
        dif_stage2<true>(z, [&](float2 v){ return p32_2(v, up); }, sg, up ? Wt[4] : ONE); }
    {   const bool up = (lane & 16) != 0; const float sg = up ? -1.0f : 1.0f;
        dif_stage2<true>(z, [](float2 v){ return swz2<SWZ_XOR16>(v); }, sg, up ? Wt[3] : ONE); }
    {   const bool up = (lane & 8) != 0;  const float sg = up ? -1.0f : 1.0f;
        dif_stage2<true>(z, [](float2 v){ return dpp2<DPP_XOR8>(v); }, sg, up ? Wt[2] : ONE); }
    {   const bool up = (lane & 4) != 0;  const float sg = up ? -1.0f : 1.0f;
        dif_stage2<true>(z, [](float2 v){ return swz2<SWZ_XOR4>(v); }, sg, up ? Wt[1] : ONE); }
    {   const bool up = (lane & 2) != 0;  const float sg = up ? -1.0f : 1.0f;
        dif_stage2<true>(z, [](float2 v){ return dpp2<DPP_XOR2>(v); }, sg, up ? Wt[0] : ONE); }
    {   const float sg = (lane & 1) ? -1.0f : 1.0f;
        dif_stage2<false>(z, [](float2 v){ return dpp2<DPP_XOR1>(v); }, sg, ONE); }
}
__device__ __forceinline__ void xfft_dit2(float2 z[2], const float2 Wt[5], int lane){
    const float2 ONE = make_float2(1.0f, 0.0f);
    {   const float sg = (lane & 1) ? -1.0f : 1.0f;
        dit_stage2<false>(z, [](float2 v){ return dpp2<DPP_XOR1>(v); }, sg, ONE); }
    {   const bool up = (lane & 2) != 0;  const float sg = up ? -1.0f : 1.0f;
        dit_stage2<true>(z, [](float2 v){ return dpp2<DPP_XOR2>(v); }, sg, up ? Wt[0] : ONE); }
    {   const bool up = (lane & 4) != 0;  const float sg = up ? -1.0f : 1.0f;
        dit_stage2<true>(z, [](float2 v){ return swz2<SWZ_XOR4>(v); }, sg, up ? Wt[1] : ONE); }
    {   const bool up = (lane & 8) != 0;  const float sg = up ? -1.0f : 1.0f;
        dit_stage2<true>(z, [](float2 v){ return dpp2<DPP_XOR8>(v); }, sg, up ? Wt[2] : ONE); }
    {   const bool up = (lane & 16) != 0; const float sg = up ? -1.0f : 1.0f;
        dit_stage2<true>(z, [](float2 v){ return swz2<SWZ_XOR16>(v); }, sg, up ? Wt[3] : ONE); }
    {   const bool up = (lane & 32) != 0; const float sg = up ? -1.0f : 1.0f;
        dit_stage2<true>(z, [&](float2 v){ return p32_2(v, up); }, sg, up ? Wt[4] : ONE); }
}

// ============================================================================
// fused v7: R14 (16 rows/block, grid 256) + COALESCED X loads.
// Dot t-ownership changed to t = 256*i + 4*lane + m (per-instruction
// contiguous float4) — valid because the 64-lane reduction is t-order
// independent. a stored to LDS in SoA (are/aim) indexed by t; the chain's
// scatter store is a one-time ~32-way conflict (~100 cyc, negligible).
// ============================================================================
__global__ __launch_bounds__(1024, 1)
void fused_kernel(const float* __restrict__ X,
                  const float* __restrict__ W,
                  float* __restrict__ out)
{
    __shared__ float2 xb0[16 * 64];    // exchange buffer A (8 KiB)
    __shared__ float2 xb1[16 * 64];    // exchange buffer B (8 KiB)
    __shared__ float  are[TLEN];       // a real, natural t (4 KiB)
    __shared__ float  aim[TLEN];       // a imag, natural t (4 KiB)

    const int lane = threadIdx.x & 63;
    const int wid  = threadIdx.x >> 6;   // 0..15
    const int row  = blockIdx.x * 16 + wid;

    // ---- prefetch own row of X, COALESCED: instr i, lane l -> float4 #(64i+l) ----
    float4 xr[4];
    {
        const float4* px = (const float4*)(X + (size_t)row * TLEN);
        #pragma unroll
        for (int i = 0; i < 4; ++i) xr[i] = px[i * 64 + lane];
    }

    if (wid < 8){
        // ================= prep chain (waves 0-7), verbatim R12/R14 =================
        const int c = bitrev6(lane);
        float2 Wt[5];
        #pragma unroll
        for (int k = 0; k < 5; ++k){
            const int h = 2 << k;
            float sv, cv;
            __sincosf(-3.14159265358979323846f * (float)(lane & (h - 1)) / (float)h, &sv, &cv);
            Wt[k] = make_float2(cv, sv);
        }
        float2 w16;
        {
            float sv, cv;
            __sincosf(-3.14159265358979323846f * (float)wid / 8.0f, &sv, &cv);
            w16 = make_float2(cv, sv);
        }
        float2 wmv[2];
        {
            const float theta = -6.28318530717958647692f * (float)c / 1024.0f;
            float sv, cv;
            __sincosf(theta * (float)(2 * wid), &sv, &cv); wmv[0] = make_float2(cv, sv);
            __sincosf(theta, &sv, &cv);                    wmv[1] = cmul(wmv[0], make_float2(cv, sv));
        }

        float2 z[2];
        z[0] = make_float2(1.0f, 0.0f);   // F e0 (uniform)
        z[1] = make_float2(1.0f, 0.0f);

        auto Mstr = [&](){
            const bool upm = (lane & 32) != 0;
            const float sgm = upm ? -1.0f : 1.0f;
            #pragma unroll
            for (int j = 0; j < 2; ++j){
                float2 o = p32_2(z[j], upm);
                z[j] = make_float2(fmaf(sgm, z[j].x, o.x), fmaf(sgm, z[j].y, o.y));
            }
        };
        auto Mcon = [&](){
            float2 a0 = z[0], b0 = z[1];
            z[0] = cadd(a0, b0); z[1] = csub(a0, b0);
        };
        auto Dstr = [&](int l){  // t = 64*(wid + 8j) + c
            const float* p = W + l * TLEN + c + 64 * wid;
            #pragma unroll
            for (int j = 0; j < 2; ++j){
                float sv, cv; __sincosf(p[j << 9], &sv, &cv);
                z[j] = cmul(z[j], make_float2(cv, sv));
            }
        };
        auto Dcon = [&](int l){  // t = 16*lane + 2*wid + j
            float2 wv = *(const float2*)(W + l * TLEN + 16 * lane + 2 * wid);
            float ws[2] = {wv.x, wv.y};
            #pragma unroll
            for (int j = 0; j < 2; ++j){
                float sv, cv; __sincosf(ws[j], &sv, &cv);
                z[j] = cmul(z[j], make_float2(cv, sv));
            }
        };
        auto midtw = [&](){
            z[0] = cmul(z[0], wmv[0]);
            z[1] = cmul(z[1], wmv[1]);
        };
        auto fft16A = [&](){
            #pragma unroll
            for (int j = 0; j < 2; ++j) xb1[(wid * 2 + j) * 64 + lane] = z[j];
            __syncthreads();
            float2 u[2];
            #pragma unroll
            for (int j = 0; j < 2; ++j){
                float2 x[8];
                #pragma unroll
                for (int w = 0; w < 8; ++w) x[w] = xb1[(2 * w + j) * 64 + lane];
                u[j] = combine8(x, wid);
            }
            u[1] = cmul(u[1], w16);
            z[0] = cadd(u[0], u[1]);
            z[1] = csub(u[0], u[1]);
        };
        auto fft16B = [&](){
            float2 u[2];
            u[0] = cadd(z[0], z[1]);
            u[1] = csub(z[0], z[1]);
            u[1] = cmul(u[1], w16);
            #pragma unroll
            for (int j = 0; j < 2; ++j) xb0[(wid * 2 + j) * 64 + lane] = u[j];
            __syncthreads();
            #pragma unroll
            for (int j = 0; j < 2; ++j){
                float2 x[8];
                #pragma unroll
                for (int w = 0; w < 8; ++w) x[w] = xb0[(2 * w + j) * 64 + lane];
                z[j] = combine8(x, wid);
            }
        };
        auto dftA = [&](){ xfft_dif2(z, Wt, lane); midtw(); fft16A(); };
        auto dftB = [&](){ fft16B(); midtw(); xfft_dit2(z, Wt, lane); };

        // chain: v = e0; for l=5..0: v = D_l M F v.  (F#1 folded into init)
        Mstr(); Dstr(5);
        #pragma unroll 1
        for (int lp = 0; lp < 2; ++lp){
            dftB(); Mcon(); Dcon(4 - 2 * lp);   // barrier 1,3
            dftA(); Mstr(); Dstr(3 - 2 * lp);   // barrier 2,4
        }
        dftB(); Mcon(); Dcon(0);                // barrier 5
        // store a in SoA natural-t layout (one-time scatter, conflicts negligible)
        #pragma unroll
        for (int j = 0; j < 2; ++j){
            int t = 16 * lane + 2 * wid + j;
            are[t] = z[j].x;
            aim[t] = z[j].y;
        }
        __syncthreads();                        // barrier 6
    } else {
        // waves 8-15: match the chain's 6 barriers
        #pragma unroll 1
        for (int b = 0; b < 6; ++b) __syncthreads();
    }

    // ================= dot phase: every wave its own row (coalesced t) =================
    float re = 0.0f, im = 0.0f;
    #pragma unroll
    for (int i = 0; i < 4; ++i){
        float4 xv = xr[i];
        float4 ar = ((const float4*)are)[i * 64 + lane];   // a_re[256i+4l .. +3]
        float4 ai = ((const float4*)aim)[i * 64 + lane];   // a_im[256i+4l .. +3]
        float xs[4] = {xv.x, xv.y, xv.z, xv.w};
        float rs[4] = {ar.x, ar.y, ar.z, ar.w};
        float is[4] = {ai.x, ai.y, ai.z, ai.w};
        #pragma unroll
        for (int m = 0; m < 4; ++m){
            float x  = fminf(fmaxf(xs[m], -0.999f), 0.999f);
            float cc = sqrtf(fmaf(-x, x, 1.0f));
            re = fmaf(rs[m], cc, re);  re = fmaf(-is[m], x,  re);
            im = fmaf(rs[m], x,  im);  im = fmaf( is[m], cc, im);
        }
    }

    float2 s = make_float2(re, im);
    s = cadd(s, dpp2<DPP_XOR1>(s));
    s = cadd(s, dpp2<DPP_XOR2>(s));
    s = cadd(s, swz2<SWZ_XOR4>(s));
    s = cadd(s, dpp2<DPP_XOR8>(s));
    s = cadd(s, swz2<SWZ_XOR16>(s));
    s = cadd(s, p32_2(s, (lane & 32) != 0));

    if (lane == 0){
        out[row] = fmaf(s.y * rsqrtf(fmaf(s.x, s.x, s.y * s.y)), 0.5f, 0.5f);
    }
}

extern "C" void kernel_launch(void* const* d_in, const int* in_sizes, int n_in,
                              void* d_out, int out_size, void* d_ws, size_t ws_size,
                              hipStream_t stream) {
    const float* X = (const float*)d_in[0];   // [4096, 1024]
    const float* W = (const float*)d_in[1];   // [6*1024]
    float* out = (float*)d_out;               // [4096]
    (void)in_sizes; (void)n_in; (void)out_size; (void)d_ws; (void)ws_size;

    fused_kernel<<<4096 / 16, 1024, 0, stream>>>(X, W, out);
}